// Round 1
// baseline (413.541 us; speedup 1.0000x reference)
//
#include <hip/hip_runtime.h>

#define N_NODES  80000
#define N_EDGES  1280000
#define N_GRAPHS 512
#define DIM      64
#define NCLS     10

#define ETILE    8192
#define NTILE    157      // ceil(N_EDGES / ETILE)
#define NCB      157      // ceil(N_NODES / 512) coarse buckets of 512 nodes
#define CBPAD    160

#define NCHUNK   4
#define CHW      16                       // dims per chunk
#define CHB      ((size_t)N_NODES * CHW)  // ushorts per chunk region (2.56MB, L2-resident)

typedef short short8f __attribute__((ext_vector_type(8)));   // 8 bf16 (4 VGPRs)
typedef float float4f __attribute__((ext_vector_type(4)));   // 4 fp32 acc
typedef unsigned uint2v __attribute__((ext_vector_type(2))); // 8B vector

static __device__ __forceinline__ unsigned short f2bf(float f) {
    unsigned u = __float_as_uint(f);
    unsigned r = (u + 0x7FFFu + ((u >> 16) & 1u)) >> 16;   // RNE
    return (unsigned short)r;
}
static __device__ __forceinline__ float bf_lo(unsigned v) { return __uint_as_float(v << 16); }
static __device__ __forceinline__ float bf_hi(unsigned v) { return __uint_as_float(v & 0xFFFF0000u); }

// ---------- Pass A: per-tile histogram over coarse buckets (no global atomics)
__global__ __launch_bounds__(256) void k_hist(const int* __restrict__ ei,
                                              int* __restrict__ hmat) {
    __shared__ int hist[NCB];
    int tile = blockIdx.x, t = threadIdx.x;
    for (int i = t; i < NCB; i += 256) hist[i] = 0;
    __syncthreads();
    int base = tile * ETILE;
    int end = base + ETILE; if (end > N_EDGES) end = N_EDGES;
    for (int i = base + t; i < end; i += 256)
        atomicAdd(&hist[ei[N_EDGES + i] >> 9], 1);
    __syncthreads();
    for (int i = t; i < NCB; i += 256) hmat[tile * CBPAD + i] = hist[i];
}

// ---------- Pass B1: per-bucket scan across tiles -> within-bucket offsets
__global__ __launch_bounds__(256) void k_scanT(const int* __restrict__ hmat,
        int* __restrict__ obase, int* __restrict__ btot) {
    __shared__ int sa[256], sb[256];
    int b = blockIdx.x, t = threadIdx.x;
    int v = (t < NTILE) ? hmat[t * CBPAD + b] : 0;
    sa[t] = v; __syncthreads();
    int* sp = sa; int* dp = sb;
    for (int off = 1; off < 256; off <<= 1) {
        dp[t] = sp[t] + ((t >= off) ? sp[t - off] : 0);
        __syncthreads();
        int* tmp = sp; sp = dp; dp = tmp;
    }
    int incl = sp[t];
    if (t < NTILE) obase[t * CBPAD + b] = incl - v;
    if (t == NTILE - 1) btot[b] = incl;
}

// ---------- Pass B2: scan bucket totals -> bucket bases
__global__ __launch_bounds__(256) void k_scanB(const int* __restrict__ btot,
        int* __restrict__ bucketbase, int* __restrict__ rowptr) {
    __shared__ int sa[256], sb[256];
    int t = threadIdx.x;
    int v = (t < NCB) ? btot[t] : 0;
    sa[t] = v; __syncthreads();
    int* sp = sa; int* dp = sb;
    for (int off = 1; off < 256; off <<= 1) {
        dp[t] = sp[t] + ((t >= off) ? sp[t - off] : 0);
        __syncthreads();
        int* tmp = sp; sp = dp; dp = tmp;
    }
    int incl = sp[t];
    if (t < NCB) bucketbase[t] = incl - v;
    if (t == 0) { bucketbase[NCB] = N_EDGES; rowptr[N_NODES] = N_EDGES; }
}

// ---------- Pass C: scatter into bucket-sorted ebuf (deterministic runs)
__global__ __launch_bounds__(256) void k_scatter(const int* __restrict__ ei,
        const int* __restrict__ obase, const int* __restrict__ bucketbase,
        int* __restrict__ ebuf) {
    __shared__ int cur[NCB];
    int tile = blockIdx.x, t = threadIdx.x;
    for (int i = t; i < NCB; i += 256)
        cur[i] = bucketbase[i] + obase[tile * CBPAD + i];
    __syncthreads();
    int base = tile * ETILE;
    int end = base + ETILE; if (end > N_EDGES) end = N_EDGES;
    for (int i = base + t; i < end; i += 256) {
        int s = ei[i], d = ei[N_EDGES + i];
        int p = atomicAdd(&cur[d >> 9], 1);
        ebuf[p] = s | ((d & 511) << 17);   // src:17 bits, local dst:9 bits
    }
}

// ---------- Pass D: per-bucket node-level CSR, all in LDS
__global__ __launch_bounds__(256) void k_csr(const int* __restrict__ ebuf,
        const int* __restrict__ bucketbase, int* __restrict__ rowptr,
        int* __restrict__ col) {
    __shared__ int cnt[512];
    __shared__ int sa[512], sb[512];
    __shared__ int cur[512];
    int b = blockIdx.x, t = threadIdx.x;
    int s = bucketbase[b], e = bucketbase[b + 1];
    cnt[t] = 0; cnt[t + 256] = 0;
    __syncthreads();
    for (int i = s + t; i < e; i += 256) atomicAdd(&cnt[ebuf[i] >> 17], 1);
    __syncthreads();
    sa[t] = cnt[t]; sa[t + 256] = cnt[t + 256];
    __syncthreads();
    int* sp = sa; int* dp = sb;
    for (int off = 1; off < 512; off <<= 1) {
        int i1 = t + 256;
        int v0 = sp[t]  + ((t  >= off) ? sp[t  - off] : 0);
        int v1 = sp[i1] + ((i1 >= off) ? sp[i1 - off] : 0);
        __syncthreads();
        dp[t] = v0; dp[i1] = v1;
        __syncthreads();
        int* tmp = sp; sp = dp; dp = tmp;
    }
    int node0 = b * 512;
    int base0 = s + sp[t] - cnt[t];
    int base1 = s + sp[t + 256] - cnt[t + 256];
    cur[t] = base0; cur[t + 256] = base1;
    if (node0 + t < N_NODES)       rowptr[node0 + t] = base0;
    if (node0 + t + 256 < N_NODES) rowptr[node0 + t + 256] = base1;
    __syncthreads();
    for (int i = s + t; i < e; i += 256) {
        int pk = ebuf[i];
        int p = atomicAdd(&cur[pk >> 17], 1);
        col[p] = pk & 0x1FFFF;
    }
}

// ---------- prep: cast x -> bf16 CHUNK-MAJOR [4][N][16] (blocks 0..4999)
// + pack W1/W2 into MFMA B-frag order bf16 (blocks 5000..5063)
__global__ __launch_bounds__(256) void k_prep2(const float* __restrict__ x,
        const float* __restrict__ wr1, const float* __restrict__ wo1,
        const float* __restrict__ wr2, const float* __restrict__ wo2,
        unsigned short* __restrict__ xb, unsigned short* __restrict__ wf) {
    int bid = blockIdx.x, t = threadIdx.x;
    if (bid < 5000) {
        int i = bid * 256 + t;                  // N_NODES*16 float4s
        int node = i >> 4, f4 = i & 15;         // dims [f4*4, f4*4+4)
        float4 v = ((const float4*)x)[i];
        ushort4 o;
        o.x = f2bf(v.x); o.y = f2bf(v.y); o.z = f2bf(v.z); o.w = f2bf(v.w);
        // chunk = f4>>2, ushort4 slot within chunk row = f4&3
        ((ushort4*)xb)[(size_t)(f4 >> 2) * (N_NODES * 4) + (size_t)node * 4 + (f4 & 3)] = o;
    } else {
        int idx = (bid - 5000) * 256 + t;       // < 2*8192
        int j = idx & 7, lane = (idx >> 3) & 63;
        int ks = (idx >> 9) & 3, nt = (idx >> 11) & 3, l = idx >> 13;
        int k = ks * 32 + ((lane >> 4) & 3) * 8 + j;
        int n = nt * 16 + (lane & 15);
        const float* wr = (l == 0) ? wr1 : wr2;
        const float* wo = (l == 0) ? wo1 : wo2;
        float val = (k < 64) ? wr[n * 64 + k] : wo[n * 64 + (k - 64)];
        wf[idx] = f2bf(val);
    }
}

// ---------- chunked aggregation: grid (N/4, 4chunks), chunk = blockIdx.y
// Phases dispatch x-major -> all CUs gather from ONE 2.56MB L2-resident region
// at a time. wave = 1 node; lane = (edge-slot e of 16, 8B sub-chunk c of 4).
__global__ __launch_bounds__(256) void k_gather_c(const unsigned short* __restrict__ Xc,
        const int* __restrict__ rowptr, const int* __restrict__ col,
        unsigned short* __restrict__ aggc) {
    int t = threadIdx.x, w = t >> 6, lane = t & 63;
    int e = lane >> 2, c = lane & 3;
    int ch = blockIdx.y;
    int node = blockIdx.x * 4 + w;
    const uint2v* Xq = (const uint2v*)(Xc + (size_t)ch * CHB);
    int start = rowptr[node], end = rowptr[node + 1];
    float a0 = 0.f, a1 = 0.f, a2 = 0.f, a3 = 0.f;
    int base = start;
    for (; base + 32 <= end; base += 32) {       // 2 loads in flight per lane
        int i0 = __builtin_nontemporal_load(col + base + e);
        int i1 = __builtin_nontemporal_load(col + base + 16 + e);
        uint2v v0 = Xq[(size_t)i0 * 4 + c];
        uint2v v1 = Xq[(size_t)i1 * 4 + c];
        a0 += bf_lo(v0.x) + bf_lo(v1.x); a1 += bf_hi(v0.x) + bf_hi(v1.x);
        a2 += bf_lo(v0.y) + bf_lo(v1.y); a3 += bf_hi(v0.y) + bf_hi(v1.y);
    }
    if (base + 16 <= end) {
        int i0 = __builtin_nontemporal_load(col + base + e);
        uint2v v0 = Xq[(size_t)i0 * 4 + c];
        a0 += bf_lo(v0.x); a1 += bf_hi(v0.x);
        a2 += bf_lo(v0.y); a3 += bf_hi(v0.y);
        base += 16;
    }
    int r = end - base;
    if (e < r) {
        int i0 = col[base + e];
        uint2v v0 = Xq[(size_t)i0 * 4 + c];
        a0 += bf_lo(v0.x); a1 += bf_hi(v0.x);
        a2 += bf_lo(v0.y); a3 += bf_hi(v0.y);
    }
#pragma unroll
    for (int off = 4; off < 64; off <<= 1) {
        a0 += __shfl_xor(a0, off); a1 += __shfl_xor(a1, off);
        a2 += __shfl_xor(a2, off); a3 += __shfl_xor(a3, off);
    }
    if (e == 0) {
        uint2v o;
        o.x = (unsigned)f2bf(a0) | ((unsigned)f2bf(a1) << 16);
        o.y = (unsigned)f2bf(a2) | ((unsigned)f2bf(a3) << 16);
        __builtin_nontemporal_store(o,
            (uint2v*)(aggc + (size_t)ch * CHB) + (size_t)node * 4 + c);
    }
}

// ---------- MFMA linear: out = act([agg|x] @ W + b), chunk-major bf16 in/out
__global__ __launch_bounds__(256) void k_linear_mfma(
        const unsigned short* __restrict__ aggb, const unsigned short* __restrict__ xb,
        const unsigned short* __restrict__ wf, const float* __restrict__ bias,
        unsigned short* __restrict__ out, int relu) {
    int t = threadIdx.x, w = t >> 6, lane = t & 63;
    int quad = lane >> 4, l15 = lane & 15;
    int mbase = blockIdx.x * 64 + w * 16;
    int m = mbase + l15;
    // A-frag dims quad*8..quad*8+7 -> chunk quad>>1, offset (quad&1)*8
    size_t roff = (size_t)m * CHW + (quad & 1) * 8;
    int qh = quad >> 1;
    short8f a0 = *(const short8f*)(aggb + (size_t)qh * CHB + roff);
    short8f a1 = *(const short8f*)(aggb + (size_t)(2 + qh) * CHB + roff);
    short8f a2 = *(const short8f*)(xb   + (size_t)qh * CHB + roff);
    short8f a3 = *(const short8f*)(xb   + (size_t)(2 + qh) * CHB + roff);
    int orow = mbase + quad * 4;
#pragma unroll
    for (int nt = 0; nt < 4; ++nt) {
        const unsigned short* wp = wf + ((size_t)(nt * 4) * 64 + lane) * 8;
        short8f b0 = *(const short8f*)(wp);
        short8f b1 = *(const short8f*)(wp + 64 * 8);
        short8f b2 = *(const short8f*)(wp + 128 * 8);
        short8f b3 = *(const short8f*)(wp + 192 * 8);
        float4f acc = {0.f, 0.f, 0.f, 0.f};
        acc = __builtin_amdgcn_mfma_f32_16x16x32_bf16(a0, b0, acc, 0, 0, 0);
        acc = __builtin_amdgcn_mfma_f32_16x16x32_bf16(a1, b1, acc, 0, 0, 0);
        acc = __builtin_amdgcn_mfma_f32_16x16x32_bf16(a2, b2, acc, 0, 0, 0);
        acc = __builtin_amdgcn_mfma_f32_16x16x32_bf16(a3, b3, acc, 0, 0, 0);
        float bi = bias[nt * 16 + l15];
        // out dim n = nt*16+l15 -> chunk nt, offset l15
#pragma unroll
        for (int r = 0; r < 4; ++r) {
            float v = acc[r] + bi;
            if (relu) v = fmaxf(v, 0.f);
            out[(size_t)nt * CHB + (size_t)(orow + r) * CHW + l15] = f2bf(v);
        }
    }
}

static __device__ __forceinline__ int lowerb(const int* a, int n, int key) {
    int lo = 0, hi = n;
    while (lo < hi) { int mid = (lo + hi) >> 1; if (a[mid] < key) lo = mid + 1; else hi = mid; }
    return lo;
}

// ---------- layer-3 collapse, stage 1: chunked per-graph partial sums
// grid (N_GRAPHS*4 parts, 4 chunks); part p covers node range [a_p, a_{p+1})
// of graph g; edges are the contiguous run [rowptr[a_p], rowptr[a_{p+1}]).
__global__ __launch_bounds__(256) void k_gsum_c(const unsigned short* __restrict__ h2,
        const int* __restrict__ rowptr, const int* __restrict__ col,
        const int* __restrict__ batch, float* __restrict__ S4) {
    __shared__ float red1[32][16];
    __shared__ float red2[32][16];
    int ch = blockIdx.y;
    int g = blockIdx.x >> 2, part = blockIdx.x & 3;
    int t = threadIdx.x;
    int hw = t >> 3, c = t & 7;                  // 32 edge slots x 8 uints(32B)
    const unsigned* Xu = (const unsigned*)(h2 + (size_t)ch * CHB);
    int ns = lowerb(batch, N_NODES, g);
    int ne = lowerb(batch, N_NODES, g + 1);
    int a0 = ns + (int)(((long long)(ne - ns) * part) >> 2);
    int a1 = ns + (int)(((long long)(ne - ns) * (part + 1)) >> 2);
    int es = rowptr[a0], ee = rowptr[a1];
    float alo = 0.f, ahi = 0.f;
    int nfull = (ee - es) >> 7;                  // full 128-edge superblocks
    int e0 = es + hw;
    for (int b = 0; b < nfull; ++b, e0 += 128) {
        int i0 = __builtin_nontemporal_load(col + e0);
        int i1 = __builtin_nontemporal_load(col + e0 + 32);
        int i2 = __builtin_nontemporal_load(col + e0 + 64);
        int i3 = __builtin_nontemporal_load(col + e0 + 96);
        unsigned v0 = Xu[(size_t)i0 * 8 + c];
        unsigned v1 = Xu[(size_t)i1 * 8 + c];
        unsigned v2 = Xu[(size_t)i2 * 8 + c];
        unsigned v3 = Xu[(size_t)i3 * 8 + c];
        alo += bf_lo(v0) + bf_lo(v1) + bf_lo(v2) + bf_lo(v3);
        ahi += bf_hi(v0) + bf_hi(v1) + bf_hi(v2) + bf_hi(v3);
    }
    for (int e2 = es + nfull * 128 + hw; e2 < ee; e2 += 32) {
        unsigned v = Xu[(size_t)col[e2] * 8 + c];
        alo += bf_lo(v); ahi += bf_hi(v);
    }
    float blo = 0.f, bhi = 0.f;
    for (int i = a0 + hw; i < a1; i += 32) {
        unsigned v = Xu[(size_t)i * 8 + c];
        blo += bf_lo(v); bhi += bf_hi(v);
    }
    red1[hw][2 * c] = alo; red1[hw][2 * c + 1] = ahi;
    red2[hw][2 * c] = blo; red2[hw][2 * c + 1] = bhi;
    __syncthreads();
    if (t < 16) {
        float v = 0.f;
#pragma unroll
        for (int s = 0; s < 32; ++s) v += red1[s][t];
        S4[(((size_t)g * 4 + ch) * 4 + part) * 32 + t] = v;
    } else if (t < 32) {
        float v = 0.f;
#pragma unroll
        for (int s = 0; s < 32; ++s) v += red2[s][t - 16];
        S4[(((size_t)g * 4 + ch) * 4 + part) * 32 + 16 + (t - 16)] = v;
    }
}

// ---------- layer-3 collapse, stage 2: pooled = S1/c @ Wr3^T + b3 + S2/c @ Wo3^T
// then out = pooled @ wlin^T + blin   (all fp32)
__global__ __launch_bounds__(64) void k_head2(const float* __restrict__ S4,
        const int* __restrict__ batch,
        const float* __restrict__ wr3, const float* __restrict__ wo3,
        const float* __restrict__ b3,
        const float* __restrict__ wlin, const float* __restrict__ blin,
        float* __restrict__ out) {
    __shared__ float s1[64], s2[64], pl[64];
    int g = blockIdx.x, t = threadIdx.x;
    int ns = lowerb(batch, N_NODES, g);
    int ne = lowerb(batch, N_NODES, g + 1);
    float inv = 1.f / (float)((ne > ns) ? (ne - ns) : 1);
    int ch = t >> 4, k = t & 15;                 // global dim t = ch*16+k
    const float* Sg = S4 + ((size_t)g * 4 + ch) * 128;
    s1[t] = (Sg[k]      + Sg[32 + k] + Sg[64 + k] + Sg[96 + k])  * inv;
    s2[t] = (Sg[16 + k] + Sg[48 + k] + Sg[80 + k] + Sg[112 + k]) * inv;
    __syncthreads();
    float acc = b3[t];
    for (int k2 = 0; k2 < 64; ++k2)
        acc += s1[k2] * wr3[t * 64 + k2] + s2[k2] * wo3[t * 64 + k2];
    pl[t] = acc;
    __syncthreads();
    float myout = 0.f;
    for (int cls = 0; cls < NCLS; ++cls) {
        float vv = pl[t] * wlin[cls * 64 + t];
        for (int off = 32; off > 0; off >>= 1) vv += __shfl_xor(vv, off);
        if (t == cls) myout = vv + blin[cls];
    }
    if (t < NCLS) out[g * NCLS + t] = myout;
}

extern "C" void kernel_launch(void* const* d_in, const int* in_sizes, int n_in,
                              void* d_out, int out_size, void* d_ws, size_t ws_size,
                              hipStream_t stream) {
    const float* x     = (const float*)d_in[0];
    const int*   ei    = (const int*)d_in[1];
    const int*   batch = (const int*)d_in[2];
    const float* wr1 = (const float*)d_in[3];
    const float* b1  = (const float*)d_in[4];
    const float* wo1 = (const float*)d_in[5];
    const float* wr2 = (const float*)d_in[6];
    const float* b2  = (const float*)d_in[7];
    const float* wo2 = (const float*)d_in[8];
    const float* wr3 = (const float*)d_in[9];
    const float* b3  = (const float*)d_in[10];
    const float* wo3 = (const float*)d_in[11];
    const float* wlin = (const float*)d_in[12];
    const float* blin = (const float*)d_in[13];
    float* out = (float*)d_out;

    char* p = (char*)d_ws;
    auto alloc = [&](size_t bytes) { char* r = p; p += (bytes + 255) & ~(size_t)255; return r; };
    int*   rowptr  = (int*)alloc((N_NODES + 1) * sizeof(int));
    int*   hmat    = (int*)alloc((size_t)NTILE * CBPAD * sizeof(int));
    int*   obase   = (int*)alloc((size_t)NTILE * CBPAD * sizeof(int));
    int*   btot    = (int*)alloc(CBPAD * sizeof(int));
    int*   bucketbase = (int*)alloc((NCB + 1) * sizeof(int));
    int*   ebuf    = (int*)alloc((size_t)N_EDGES * sizeof(int));
    int*   col     = (int*)alloc((size_t)N_EDGES * sizeof(int));
    unsigned short* wf  = (unsigned short*)alloc(2 * 8192 * sizeof(unsigned short));
    unsigned short* xbf = (unsigned short*)alloc((size_t)N_NODES * 64 * 2);
    unsigned short* agg = (unsigned short*)alloc((size_t)N_NODES * 64 * 2);
    unsigned short* hA  = (unsigned short*)alloc((size_t)N_NODES * 64 * 2);
    unsigned short* hB  = (unsigned short*)alloc((size_t)N_NODES * 64 * 2);
    float* S4      = (float*)alloc((size_t)N_GRAPHS * 4 * 128 * sizeof(float));

    // CSR build: deterministic two-level counting sort, zero global atomics
    k_hist   <<<NTILE, 256, 0, stream>>>(ei, hmat);
    k_scanT  <<<NCB,   256, 0, stream>>>(hmat, obase, btot);
    k_scanB  <<<1,     256, 0, stream>>>(btot, bucketbase, rowptr);
    k_scatter<<<NTILE, 256, 0, stream>>>(ei, obase, bucketbase, ebuf);
    k_csr    <<<NCB,   256, 0, stream>>>(ebuf, bucketbase, rowptr, col);
    k_prep2  <<<5064,  256, 0, stream>>>(x, wr1, wo1, wr2, wo2, xbf, wf);

    // layer 1
    k_gather_c   <<<dim3(N_NODES / 4, NCHUNK), 256, 0, stream>>>(xbf, rowptr, col, agg);
    k_linear_mfma<<<N_NODES / 64, 256, 0, stream>>>(agg, xbf, wf,        b1, hA, 1);
    // layer 2
    k_gather_c   <<<dim3(N_NODES / 4, NCHUNK), 256, 0, stream>>>(hA, rowptr, col, agg);
    k_linear_mfma<<<N_NODES / 64, 256, 0, stream>>>(agg, hA, wf + 8192,  b2, hB, 1);
    // layer 3 + pool collapsed: chunked per-graph partial sums, tiny head
    k_gsum_c<<<dim3(N_GRAPHS * 4, NCHUNK), 256, 0, stream>>>(hB, rowptr, col, batch, S4);
    k_head2 <<<N_GRAPHS, 64, 0, stream>>>(S4, batch, wr3, wo3, b3, wlin, blin, out);
}

// Round 2
// 261.703 us; speedup vs baseline: 1.5802x; 1.5802x over previous
//
#include <hip/hip_runtime.h>

#define N_NODES  80000
#define N_EDGES  1280000
#define N_GRAPHS 512
#define DIM      64
#define NCLS     10

#define ETILE    8192
#define NTILE    157      // ceil(N_EDGES / ETILE)
#define NCB      157      // ceil(N_NODES / 512) coarse buckets of 512 nodes
#define CBPAD    160

typedef short short8f __attribute__((ext_vector_type(8)));   // 8 bf16 (4 VGPRs)
typedef float float4f __attribute__((ext_vector_type(4)));   // 4 fp32 acc

static __device__ __forceinline__ unsigned short f2bf(float f) {
    unsigned u = __float_as_uint(f);
    unsigned r = (u + 0x7FFFu + ((u >> 16) & 1u)) >> 16;   // RNE
    return (unsigned short)r;
}
static __device__ __forceinline__ float bf_lo(unsigned v) { return __uint_as_float(v << 16); }
static __device__ __forceinline__ float bf_hi(unsigned v) { return __uint_as_float(v & 0xFFFF0000u); }

// ---------- Pass A (merged): blocks [0,NTILE) per-tile histogram over coarse
// buckets; blocks [NTILE, NTILE+5000) cast x->bf16; rest pack W1/W2 MFMA frags.
__global__ __launch_bounds__(256) void k_histprep(const int* __restrict__ ei,
        const float* __restrict__ x,
        const float* __restrict__ wr1, const float* __restrict__ wo1,
        const float* __restrict__ wr2, const float* __restrict__ wo2,
        int* __restrict__ hmat, unsigned short* __restrict__ xb,
        unsigned short* __restrict__ wf) {
    __shared__ int hist[NCB];
    int bid = blockIdx.x, t = threadIdx.x;
    if (bid < NTILE) {
        int tile = bid;
        for (int i = t; i < NCB; i += 256) hist[i] = 0;
        __syncthreads();
        int base = tile * ETILE;
        int end = base + ETILE; if (end > N_EDGES) end = N_EDGES;
        for (int i = base + t; i < end; i += 256)
            atomicAdd(&hist[ei[N_EDGES + i] >> 9], 1);
        __syncthreads();
        for (int i = t; i < NCB; i += 256) hmat[tile * CBPAD + i] = hist[i];
        return;
    }
    int pb = bid - NTILE;
    if (pb < 5000) {
        int i = pb * 256 + t;                   // N_NODES*16 float4s
        float4 v = ((const float4*)x)[i];
        ushort4 o;
        o.x = f2bf(v.x); o.y = f2bf(v.y); o.z = f2bf(v.z); o.w = f2bf(v.w);
        ((ushort4*)xb)[i] = o;
    } else {
        int idx = (pb - 5000) * 256 + t;        // < 2*8192
        int j = idx & 7, lane = (idx >> 3) & 63;
        int ks = (idx >> 9) & 3, nt = (idx >> 11) & 3, l = idx >> 13;
        int k = ks * 32 + ((lane >> 4) & 3) * 8 + j;
        int n = nt * 16 + (lane & 15);
        const float* wr = (l == 0) ? wr1 : wr2;
        const float* wo = (l == 0) ? wo1 : wo2;
        float val = (k < 64) ? wr[n * 64 + k] : wo[n * 64 + (k - 64)];
        wf[idx] = f2bf(val);
    }
}

// ---------- Pass B1: per-bucket scan across tiles -> within-bucket offsets
__global__ __launch_bounds__(256) void k_scanT(const int* __restrict__ hmat,
        int* __restrict__ obase, int* __restrict__ btot) {
    __shared__ int sa[256], sb[256];
    int b = blockIdx.x, t = threadIdx.x;
    int v = (t < NTILE) ? hmat[t * CBPAD + b] : 0;
    sa[t] = v; __syncthreads();
    int* sp = sa; int* dp = sb;
    for (int off = 1; off < 256; off <<= 1) {
        dp[t] = sp[t] + ((t >= off) ? sp[t - off] : 0);
        __syncthreads();
        int* tmp = sp; sp = dp; dp = tmp;
    }
    int incl = sp[t];
    if (t < NTILE) obase[t * CBPAD + b] = incl - v;
    if (t == NTILE - 1) btot[b] = incl;
}

// ---------- Pass C: scatter into bucket-sorted ebuf (deterministic runs)
// bucket bases re-derived locally from btot (157 ints) — k_scanB eliminated
__global__ __launch_bounds__(256) void k_scatter2(const int* __restrict__ ei,
        const int* __restrict__ obase, const int* __restrict__ btot,
        int* __restrict__ ebuf) {
    __shared__ int sa[256], sb[256];
    __shared__ int cur[NCB];
    int tile = blockIdx.x, t = threadIdx.x;
    int v = (t < NCB) ? btot[t] : 0;
    sa[t] = v; __syncthreads();
    int* sp = sa; int* dp = sb;
    for (int off = 1; off < 256; off <<= 1) {
        dp[t] = sp[t] + ((t >= off) ? sp[t - off] : 0);
        __syncthreads();
        int* tmp = sp; sp = dp; dp = tmp;
    }
    if (t < NCB) cur[t] = (sp[t] - v) + obase[tile * CBPAD + t];
    __syncthreads();
    int base = tile * ETILE;
    int end = base + ETILE; if (end > N_EDGES) end = N_EDGES;
    for (int i = base + t; i < end; i += 256) {
        int s = ei[i], d = ei[N_EDGES + i];
        int p = atomicAdd(&cur[d >> 9], 1);
        ebuf[p] = s | ((d & 511) << 17);   // src:17 bits, local dst:9 bits
    }
}

// ---------- Pass D: per-bucket node-level CSR, all in LDS
__global__ __launch_bounds__(256) void k_csr2(const int* __restrict__ ebuf,
        const int* __restrict__ btot, int* __restrict__ rowptr,
        int* __restrict__ col) {
    __shared__ int cnt[512];
    __shared__ int sa[512], sb[512];
    __shared__ int cur[512];
    int b = blockIdx.x, t = threadIdx.x;
    // local exclusive scan of btot -> this bucket's edge range [s, e)
    int v = (t < NCB) ? btot[t] : 0;
    sa[t] = v; __syncthreads();
    int* sp = sa; int* dp = sb;
    for (int off = 1; off < 256; off <<= 1) {
        dp[t] = sp[t] + ((t >= off) ? sp[t - off] : 0);
        __syncthreads();
        int* tmp = sp; sp = dp; dp = tmp;
    }
    int e = sp[b];
    int s = e - btot[b];
    if (b == 0 && t == 0) rowptr[N_NODES] = N_EDGES;
    __syncthreads();
    cnt[t] = 0; cnt[t + 256] = 0;
    __syncthreads();
    for (int i = s + t; i < e; i += 256) atomicAdd(&cnt[ebuf[i] >> 17], 1);
    __syncthreads();
    sa[t] = cnt[t]; sa[t + 256] = cnt[t + 256];
    __syncthreads();
    sp = sa; dp = sb;
    for (int off = 1; off < 512; off <<= 1) {
        int i1 = t + 256;
        int v0 = sp[t]  + ((t  >= off) ? sp[t  - off] : 0);
        int v1 = sp[i1] + ((i1 >= off) ? sp[i1 - off] : 0);
        __syncthreads();
        dp[t] = v0; dp[i1] = v1;
        __syncthreads();
        int* tmp = sp; sp = dp; dp = tmp;
    }
    int node0 = b * 512;
    int base0 = s + sp[t] - cnt[t];
    int base1 = s + sp[t + 256] - cnt[t + 256];
    cur[t] = base0; cur[t + 256] = base1;
    if (node0 + t < N_NODES)       rowptr[node0 + t] = base0;
    if (node0 + t + 256 < N_NODES) rowptr[node0 + t + 256] = base1;
    __syncthreads();
    for (int i = s + t; i < e; i += 256) {
        int pk = ebuf[i];
        int p = atomicAdd(&cur[pk >> 17], 1);
        col[p] = pk & 0x1FFFF;
    }
}

// ---------- fused gather + MFMA linear: block = 64 nodes, wave = 16 nodes.
// Phase 1: round-0 gather inner loop (8 edge slots x 8 uint4 chunks per lane),
// rows parked in LDS (9-uint4 pad -> no 128B-stride bank conflict).
// Phase 2: round-0 MFMA epilogue. Wave-private LDS rows -> no barrier needed.
__global__ __launch_bounds__(256) void k_gatherlin(
        const unsigned short* __restrict__ Xin,
        const int* __restrict__ rowptr, const int* __restrict__ col,
        const unsigned short* __restrict__ wf, const float* __restrict__ bias,
        unsigned short* __restrict__ out, int relu) {
    __shared__ uint4 sAgg[64][9];
    const uint4* Xq = (const uint4*)Xin;
    int t = threadIdx.x, w = t >> 6, lane = t & 63;
    int e = lane >> 3, c = lane & 7;
    int nb = blockIdx.x * 64 + w * 16;          // first node of this wave
    int rp = (lane <= 16) ? rowptr[nb + lane] : 0;
    for (int n = 0; n < 16; ++n) {
        int start = __shfl(rp, n), end = __shfl(rp, n + 1);
        float acc[8] = {0.f, 0.f, 0.f, 0.f, 0.f, 0.f, 0.f, 0.f};
        int base = start;
        for (; base + 16 <= end; base += 16) {   // 2 uint4 loads in flight
            int i0 = col[base + e];
            int i1 = col[base + 8 + e];
            uint4 v0 = Xq[(size_t)i0 * 8 + c];
            uint4 v1 = Xq[(size_t)i1 * 8 + c];
            acc[0] += bf_lo(v0.x) + bf_lo(v1.x); acc[1] += bf_hi(v0.x) + bf_hi(v1.x);
            acc[2] += bf_lo(v0.y) + bf_lo(v1.y); acc[3] += bf_hi(v0.y) + bf_hi(v1.y);
            acc[4] += bf_lo(v0.z) + bf_lo(v1.z); acc[5] += bf_hi(v0.z) + bf_hi(v1.z);
            acc[6] += bf_lo(v0.w) + bf_lo(v1.w); acc[7] += bf_hi(v0.w) + bf_hi(v1.w);
        }
        for (; base + 8 <= end; base += 8) {
            int i0 = col[base + e];
            uint4 v0 = Xq[(size_t)i0 * 8 + c];
            acc[0] += bf_lo(v0.x); acc[1] += bf_hi(v0.x);
            acc[2] += bf_lo(v0.y); acc[3] += bf_hi(v0.y);
            acc[4] += bf_lo(v0.z); acc[5] += bf_hi(v0.z);
            acc[6] += bf_lo(v0.w); acc[7] += bf_hi(v0.w);
        }
        int r = end - base;
        if (e < r) {
            int i0 = col[base + e];
            uint4 v0 = Xq[(size_t)i0 * 8 + c];
            acc[0] += bf_lo(v0.x); acc[1] += bf_hi(v0.x);
            acc[2] += bf_lo(v0.y); acc[3] += bf_hi(v0.y);
            acc[4] += bf_lo(v0.z); acc[5] += bf_hi(v0.z);
            acc[6] += bf_lo(v0.w); acc[7] += bf_hi(v0.w);
        }
#pragma unroll
        for (int off = 8; off < 64; off <<= 1) {
#pragma unroll
            for (int j = 0; j < 8; ++j) acc[j] += __shfl_xor(acc[j], off);
        }
        if (e == 0) {
            uint4 o;
            o.x = (unsigned)f2bf(acc[0]) | ((unsigned)f2bf(acc[1]) << 16);
            o.y = (unsigned)f2bf(acc[2]) | ((unsigned)f2bf(acc[3]) << 16);
            o.z = (unsigned)f2bf(acc[4]) | ((unsigned)f2bf(acc[5]) << 16);
            o.w = (unsigned)f2bf(acc[6]) | ((unsigned)f2bf(acc[7]) << 16);
            sAgg[w * 16 + n][c] = o;
        }
    }
    // phase 2: out = act([agg|x] @ W + b)  (wave-private rows; lgkmcnt only)
    int quad = lane >> 4, l15 = lane & 15;
    int m = nb + l15;
    short8f a0 = *(const short8f*)&sAgg[w * 16 + l15][quad];
    short8f a1 = *(const short8f*)&sAgg[w * 16 + l15][4 + quad];
    const unsigned short* xr = Xin + (size_t)m * 64;
    short8f a2 = *(const short8f*)(xr + quad * 8);
    short8f a3 = *(const short8f*)(xr + 32 + quad * 8);
    int orow = nb + quad * 4;
#pragma unroll
    for (int nt = 0; nt < 4; ++nt) {
        const unsigned short* wp = wf + ((size_t)(nt * 4) * 64 + lane) * 8;
        short8f b0 = *(const short8f*)(wp);
        short8f b1 = *(const short8f*)(wp + 64 * 8);
        short8f b2 = *(const short8f*)(wp + 128 * 8);
        short8f b3 = *(const short8f*)(wp + 192 * 8);
        float4f acc = {0.f, 0.f, 0.f, 0.f};
        acc = __builtin_amdgcn_mfma_f32_16x16x32_bf16(a0, b0, acc, 0, 0, 0);
        acc = __builtin_amdgcn_mfma_f32_16x16x32_bf16(a1, b1, acc, 0, 0, 0);
        acc = __builtin_amdgcn_mfma_f32_16x16x32_bf16(a2, b2, acc, 0, 0, 0);
        acc = __builtin_amdgcn_mfma_f32_16x16x32_bf16(a3, b3, acc, 0, 0, 0);
        float bi = bias[nt * 16 + l15];
#pragma unroll
        for (int r = 0; r < 4; ++r) {
            float v = acc[r] + bi;
            if (relu) v = fmaxf(v, 0.f);
            out[(size_t)(orow + r) * 64 + nt * 16 + l15] = f2bf(v);
        }
    }
}

static __device__ __forceinline__ int lowerb(const int* a, int n, int key) {
    int lo = 0, hi = n;
    while (lo < hi) { int mid = (lo + hi) >> 1; if (a[mid] < key) lo = mid + 1; else hi = mid; }
    return lo;
}

// ---------- layer-3 collapse, stage 1: per-graph partial sums, 4 parts/graph
__global__ __launch_bounds__(256) void k_gsum(const unsigned short* __restrict__ h2,
        const int* __restrict__ rowptr, const int* __restrict__ col,
        const int* __restrict__ batch, float* __restrict__ S4) {
    __shared__ float red1[8][64];
    __shared__ float red2[8][64];
    const unsigned* Xu = (const unsigned*)h2;
    int g = blockIdx.x >> 2, part = blockIdx.x & 3;
    int t = threadIdx.x;
    int hw = t >> 5, c = t & 31;
    int ns = lowerb(batch, N_NODES, g);
    int ne = lowerb(batch, N_NODES, g + 1);
    int a0 = ns + (int)(((long long)(ne - ns) * part) >> 2);
    int a1 = ns + (int)(((long long)(ne - ns) * (part + 1)) >> 2);
    int es = rowptr[a0], ee = rowptr[a1];
    float alo = 0.f, ahi = 0.f;
    int nfull = (ee - es) >> 7;            // full 128-edge superblocks
    int e0 = es + hw * 16;
    for (int b = 0; b < nfull; ++b, e0 += 128) {
        unsigned v[16];
#pragma unroll
        for (int j = 0; j < 16; ++j)
            v[j] = Xu[(size_t)col[e0 + j] * 32 + c];
#pragma unroll
        for (int j = 0; j < 16; ++j) { alo += bf_lo(v[j]); ahi += bf_hi(v[j]); }
    }
    for (int e = es + nfull * 128 + hw; e < ee; e += 8) {
        unsigned v = Xu[(size_t)col[e] * 32 + c];
        alo += bf_lo(v); ahi += bf_hi(v);
    }
    float blo = 0.f, bhi = 0.f;
    for (int i = a0 + hw; i < a1; i += 8) {
        unsigned v = Xu[(size_t)i * 32 + c];
        blo += bf_lo(v); bhi += bf_hi(v);
    }
    red1[hw][2 * c] = alo; red1[hw][2 * c + 1] = ahi;
    red2[hw][2 * c] = blo; red2[hw][2 * c + 1] = bhi;
    __syncthreads();
    if (t < 64) {
        float v = 0.f;
#pragma unroll
        for (int s = 0; s < 8; ++s) v += red1[s][t];
        S4[(size_t)blockIdx.x * 128 + t] = v;
    } else if (t < 128) {
        float v = 0.f;
#pragma unroll
        for (int s = 0; s < 8; ++s) v += red2[s][t - 64];
        S4[(size_t)blockIdx.x * 128 + 64 + (t - 64)] = v;
    }
}

// ---------- layer-3 collapse, stage 2: pooled matmuls + head (all fp32)
__global__ __launch_bounds__(64) void k_head2(const float* __restrict__ S4,
        const int* __restrict__ batch,
        const float* __restrict__ wr3, const float* __restrict__ wo3,
        const float* __restrict__ b3,
        const float* __restrict__ wlin, const float* __restrict__ blin,
        float* __restrict__ out) {
    __shared__ float s1[64], s2[64], pl[64];
    int g = blockIdx.x, t = threadIdx.x;
    int ns = lowerb(batch, N_NODES, g);
    int ne = lowerb(batch, N_NODES, g + 1);
    float inv = 1.f / (float)((ne > ns) ? (ne - ns) : 1);
    const float* Sg = S4 + (size_t)g * 4 * 128;
    s1[t] = (Sg[t]       + Sg[128 + t]       + Sg[256 + t]       + Sg[384 + t]) * inv;
    s2[t] = (Sg[64 + t]  + Sg[192 + t]       + Sg[320 + t]       + Sg[448 + t]) * inv;
    __syncthreads();
    float acc = b3[t];
    for (int k = 0; k < 64; ++k)
        acc += s1[k] * wr3[t * 64 + k] + s2[k] * wo3[t * 64 + k];
    pl[t] = acc;
    __syncthreads();
    float myout = 0.f;
    for (int cls = 0; cls < NCLS; ++cls) {
        float vv = pl[t] * wlin[cls * 64 + t];
        for (int off = 32; off > 0; off >>= 1) vv += __shfl_xor(vv, off);
        if (t == cls) myout = vv + blin[cls];
    }
    if (t < NCLS) out[g * NCLS + t] = myout;
}

extern "C" void kernel_launch(void* const* d_in, const int* in_sizes, int n_in,
                              void* d_out, int out_size, void* d_ws, size_t ws_size,
                              hipStream_t stream) {
    const float* x     = (const float*)d_in[0];
    const int*   ei    = (const int*)d_in[1];
    const int*   batch = (const int*)d_in[2];
    const float* wr1 = (const float*)d_in[3];
    const float* b1  = (const float*)d_in[4];
    const float* wo1 = (const float*)d_in[5];
    const float* wr2 = (const float*)d_in[6];
    const float* b2  = (const float*)d_in[7];
    const float* wo2 = (const float*)d_in[8];
    const float* wr3 = (const float*)d_in[9];
    const float* b3  = (const float*)d_in[10];
    const float* wo3 = (const float*)d_in[11];
    const float* wlin = (const float*)d_in[12];
    const float* blin = (const float*)d_in[13];
    float* out = (float*)d_out;

    char* p = (char*)d_ws;
    auto alloc = [&](size_t bytes) { char* r = p; p += (bytes + 255) & ~(size_t)255; return r; };
    int*   rowptr  = (int*)alloc((N_NODES + 1) * sizeof(int));
    int*   hmat    = (int*)alloc((size_t)NTILE * CBPAD * sizeof(int));
    int*   obase   = (int*)alloc((size_t)NTILE * CBPAD * sizeof(int));
    int*   btot    = (int*)alloc(CBPAD * sizeof(int));
    int*   ebuf    = (int*)alloc((size_t)N_EDGES * sizeof(int));
    int*   col     = (int*)alloc((size_t)N_EDGES * sizeof(int));
    unsigned short* wf  = (unsigned short*)alloc(2 * 8192 * sizeof(unsigned short));
    unsigned short* xbf = (unsigned short*)alloc((size_t)N_NODES * 64 * 2);
    unsigned short* hA  = (unsigned short*)alloc((size_t)N_NODES * 64 * 2);
    unsigned short* hB  = (unsigned short*)alloc((size_t)N_NODES * 64 * 2);
    float* S4      = (float*)alloc((size_t)N_GRAPHS * 4 * 128 * sizeof(float));

    // CSR build (deterministic two-level counting sort) + prep, 4 launches
    k_histprep<<<NTILE + 5064, 256, 0, stream>>>(ei, x, wr1, wo1, wr2, wo2,
                                                 hmat, xbf, wf);
    k_scanT   <<<NCB,   256, 0, stream>>>(hmat, obase, btot);
    k_scatter2<<<NTILE, 256, 0, stream>>>(ei, obase, btot, ebuf);
    k_csr2    <<<NCB,   256, 0, stream>>>(ebuf, btot, rowptr, col);

    // layers 1+2: fused gather+linear (agg round-trip eliminated)
    k_gatherlin<<<N_NODES / 64, 256, 0, stream>>>(xbf, rowptr, col, wf,        b1, hA, 1);
    k_gatherlin<<<N_NODES / 64, 256, 0, stream>>>(hA,  rowptr, col, wf + 8192, b2, hB, 1);

    // layer 3 + pool collapsed
    k_gsum <<<N_GRAPHS * 4, 256, 0, stream>>>(hB, rowptr, col, batch, S4);
    k_head2<<<N_GRAPHS,     64,  0, stream>>>(S4, batch, wr3, wo3, b3, wlin, blin, out);
}

// Round 3
// 238.716 us; speedup vs baseline: 1.7324x; 1.0963x over previous
//
#include <hip/hip_runtime.h>

#define N_NODES  80000
#define N_EDGES  1280000
#define N_GRAPHS 512
#define DIM      64
#define NCLS     10

#define ETILE    2048
#define NTILE    625      // N_EDGES / ETILE exactly
#define NCB      313      // ceil(N_NODES / 256) buckets of 256 nodes
#define CBPAD    320

typedef _Float16 half8f __attribute__((ext_vector_type(8)));  // 8 f16 (4 VGPRs)
typedef float float4f __attribute__((ext_vector_type(4)));    // 4 fp32 acc

static __device__ __forceinline__ unsigned short f2h(float f) {
    _Float16 h = (_Float16)f;                 // v_cvt_f16_f32, RNE
    return __builtin_bit_cast(unsigned short, h);
}
static __device__ __forceinline__ float h_lo(unsigned v) {
    return (float)__builtin_bit_cast(_Float16, (unsigned short)(v & 0xFFFF));
}
static __device__ __forceinline__ float h_hi(unsigned v) {
    return (float)__builtin_bit_cast(_Float16, (unsigned short)(v >> 16));
}

// ---------- Pass A (merged): blocks [0,NTILE) per-tile histogram over coarse
// buckets; blocks [NTILE, NTILE+5000) cast x->f16; rest pack W1/W2 MFMA frags.
__global__ __launch_bounds__(256) void k_histprep(const int* __restrict__ ei,
        const float* __restrict__ x,
        const float* __restrict__ wr1, const float* __restrict__ wo1,
        const float* __restrict__ wr2, const float* __restrict__ wo2,
        int* __restrict__ hmat, unsigned short* __restrict__ xb,
        unsigned short* __restrict__ wf) {
    __shared__ int hist[NCB];
    int bid = blockIdx.x, t = threadIdx.x;
    if (bid < NTILE) {
        int tile = bid;
        for (int i = t; i < NCB; i += 256) hist[i] = 0;
        __syncthreads();
        int base = tile * ETILE;
        int end = base + ETILE;
        for (int i = base + t; i < end; i += 256)
            atomicAdd(&hist[ei[N_EDGES + i] >> 8], 1);
        __syncthreads();
        for (int i = t; i < NCB; i += 256) hmat[tile * CBPAD + i] = hist[i];
        return;
    }
    int pb = bid - NTILE;
    if (pb < 5000) {
        int i = pb * 256 + t;                   // N_NODES*16 float4s
        float4 v = ((const float4*)x)[i];
        ushort4 o;
        o.x = f2h(v.x); o.y = f2h(v.y); o.z = f2h(v.z); o.w = f2h(v.w);
        ((ushort4*)xb)[i] = o;
    } else {
        int idx = (pb - 5000) * 256 + t;        // < 2*8192
        int j = idx & 7, lane = (idx >> 3) & 63;
        int ks = (idx >> 9) & 3, nt = (idx >> 11) & 3, l = idx >> 13;
        int k = ks * 32 + ((lane >> 4) & 3) * 8 + j;
        int n = nt * 16 + (lane & 15);
        const float* wr = (l == 0) ? wr1 : wr2;
        const float* wo = (l == 0) ? wo1 : wo2;
        float val = (k < 64) ? wr[n * 64 + k] : wo[n * 64 + (k - 64)];
        wf[idx] = f2h(val);
    }
}

// ---------- Pass B: per-bucket exclusive scan across 625 tiles (3 elems/thr)
__global__ __launch_bounds__(256) void k_scanT(const int* __restrict__ hmat,
        int* __restrict__ obase, int* __restrict__ btot) {
    __shared__ int sa[256], sb[256];
    int b = blockIdx.x, t = threadIdx.x;
    int j0 = 3 * t;
    int l0 = (j0     < NTILE) ? hmat[(j0    ) * CBPAD + b] : 0;
    int l1 = (j0 + 1 < NTILE) ? hmat[(j0 + 1) * CBPAD + b] : 0;
    int l2 = (j0 + 2 < NTILE) ? hmat[(j0 + 2) * CBPAD + b] : 0;
    int s = l0 + l1 + l2;
    sa[t] = s; __syncthreads();
    int* sp = sa; int* dp = sb;
    for (int off = 1; off < 256; off <<= 1) {
        dp[t] = sp[t] + ((t >= off) ? sp[t - off] : 0);
        __syncthreads();
        int* tmp = sp; sp = dp; dp = tmp;
    }
    int ex = sp[t] - s;
    if (j0     < NTILE) obase[(j0    ) * CBPAD + b] = ex;
    if (j0 + 1 < NTILE) obase[(j0 + 1) * CBPAD + b] = ex + l0;
    if (j0 + 2 < NTILE) obase[(j0 + 2) * CBPAD + b] = ex + l0 + l1;
    if (t == 255) btot[b] = sp[255];
}

// ---------- Pass C: scatter into bucket-sorted ebuf (deterministic runs)
// bucket bases re-derived locally from btot[313] (2 elems/thread scan)
__global__ __launch_bounds__(256) void k_scatter2(const int* __restrict__ ei,
        const int* __restrict__ obase, const int* __restrict__ btot,
        int* __restrict__ ebuf) {
    __shared__ int sa[256], sb[256];
    __shared__ int bbase[NCB];
    __shared__ int cur[NCB];
    int tile = blockIdx.x, t = threadIdx.x;
    int l0 = (2 * t     < NCB) ? btot[2 * t]     : 0;
    int l1 = (2 * t + 1 < NCB) ? btot[2 * t + 1] : 0;
    int s = l0 + l1;
    sa[t] = s; __syncthreads();
    int* sp = sa; int* dp = sb;
    for (int off = 1; off < 256; off <<= 1) {
        dp[t] = sp[t] + ((t >= off) ? sp[t - off] : 0);
        __syncthreads();
        int* tmp = sp; sp = dp; dp = tmp;
    }
    int ex = sp[t] - s;
    if (2 * t     < NCB) bbase[2 * t]     = ex;
    if (2 * t + 1 < NCB) bbase[2 * t + 1] = ex + l0;
    __syncthreads();
    for (int i = t; i < NCB; i += 256)
        cur[i] = bbase[i] + obase[tile * CBPAD + i];
    __syncthreads();
    int base = tile * ETILE;
    int end = base + ETILE;
    for (int i = base + t; i < end; i += 256) {
        int sv = ei[i], d = ei[N_EDGES + i];
        int p = atomicAdd(&cur[d >> 8], 1);
        ebuf[p] = sv | ((d & 255) << 17);   // src:17 bits, local dst:8 bits
    }
}

// ---------- Pass D: per-bucket node-level CSR (256-node buckets), all in LDS
__global__ __launch_bounds__(256) void k_csr2(const int* __restrict__ ebuf,
        const int* __restrict__ btot, int* __restrict__ rowptr,
        int* __restrict__ col) {
    __shared__ int sa[256], sb[256];
    __shared__ int bbase[NCB];
    __shared__ int cnt[256], cur[256];
    int b = blockIdx.x, t = threadIdx.x;
    int l0 = (2 * t     < NCB) ? btot[2 * t]     : 0;
    int l1 = (2 * t + 1 < NCB) ? btot[2 * t + 1] : 0;
    int sm = l0 + l1;
    sa[t] = sm; __syncthreads();
    int* sp = sa; int* dp = sb;
    for (int off = 1; off < 256; off <<= 1) {
        dp[t] = sp[t] + ((t >= off) ? sp[t - off] : 0);
        __syncthreads();
        int* tmp = sp; sp = dp; dp = tmp;
    }
    int ex = sp[t] - sm;
    if (2 * t     < NCB) bbase[2 * t]     = ex;
    if (2 * t + 1 < NCB) bbase[2 * t + 1] = ex + l0;
    cnt[t] = 0;
    __syncthreads();
    int s = bbase[b];
    int e = s + btot[b];
    for (int i = s + t; i < e; i += 256) atomicAdd(&cnt[ebuf[i] >> 17], 1);
    __syncthreads();
    int c = cnt[t];
    sa[t] = c; __syncthreads();
    sp = sa; dp = sb;
    for (int off = 1; off < 256; off <<= 1) {
        dp[t] = sp[t] + ((t >= off) ? sp[t - off] : 0);
        __syncthreads();
        int* tmp = sp; sp = dp; dp = tmp;
    }
    int rowbase = s + sp[t] - c;
    cur[t] = rowbase;
    int node = b * 256 + t;
    if (node <= N_NODES) rowptr[node] = rowbase;   // bucket 312/t=128 writes sentinel
    __syncthreads();
    for (int i = s + t; i < e; i += 256) {
        int pk = ebuf[i];
        int p = atomicAdd(&cur[pk >> 17], 1);
        col[p] = pk & 0x1FFFF;
    }
}

// ---------- fused gather + MFMA linear: block = 64 nodes, wave = 16 nodes.
// Phase 1: gather (8 edge slots x 8 f16x8 chunks per lane), packed f16
// accumulate (v_pk_add_f16), rows parked in padded LDS.
// Phase 2: MFMA epilogue (f16). Wave-private LDS rows -> no barrier needed.
__global__ __launch_bounds__(256) void k_gatherlin(
        const unsigned short* __restrict__ Xin,
        const int* __restrict__ rowptr, const int* __restrict__ col,
        const unsigned short* __restrict__ wf, const float* __restrict__ bias,
        unsigned short* __restrict__ out, int relu) {
    __shared__ uint4 sAgg[64][9];
    const half8f* Xq = (const half8f*)Xin;
    int t = threadIdx.x, w = t >> 6, lane = t & 63;
    int e = lane >> 3, c = lane & 7;
    int nb = blockIdx.x * 64 + w * 16;          // first node of this wave
    int rp = (lane <= 16) ? rowptr[nb + lane] : 0;
    for (int n = 0; n < 16; ++n) {
        int start = __shfl(rp, n), end = __shfl(rp, n + 1);
        half8f acc = {};
        int base = start;
        for (; base + 16 <= end; base += 16) {   // 2 16B loads in flight
            int i0 = col[base + e];
            int i1 = col[base + 8 + e];
            half8f v0 = Xq[(size_t)i0 * 8 + c];
            half8f v1 = Xq[(size_t)i1 * 8 + c];
            acc = acc + v0;
            acc = acc + v1;
        }
        for (; base + 8 <= end; base += 8) {
            int i0 = col[base + e];
            acc = acc + Xq[(size_t)i0 * 8 + c];
        }
        int r = end - base;
        if (e < r) {
            int i0 = col[base + e];
            acc = acc + Xq[(size_t)i0 * 8 + c];
        }
#pragma unroll
        for (int off = 8; off < 64; off <<= 1) {
            uint4 au = __builtin_bit_cast(uint4, acc);
            uint4 bu;
            bu.x = __shfl_xor(au.x, off); bu.y = __shfl_xor(au.y, off);
            bu.z = __shfl_xor(au.z, off); bu.w = __shfl_xor(au.w, off);
            acc = acc + __builtin_bit_cast(half8f, bu);
        }
        if (e == 0) sAgg[w * 16 + n][c] = __builtin_bit_cast(uint4, acc);
    }
    // phase 2: out = act([agg|x] @ W + b)  (wave-private rows; lgkmcnt only)
    int quad = lane >> 4, l15 = lane & 15;
    int m = nb + l15;
    half8f a0 = *(const half8f*)&sAgg[w * 16 + l15][quad];
    half8f a1 = *(const half8f*)&sAgg[w * 16 + l15][4 + quad];
    const half8f* xr = (const half8f*)(Xin + (size_t)m * 64);
    half8f a2 = xr[quad];
    half8f a3 = xr[4 + quad];
    int orow = nb + quad * 4;
#pragma unroll
    for (int nt = 0; nt < 4; ++nt) {
        const half8f* wp = (const half8f*)(wf + ((size_t)(nt * 4) * 64 + lane) * 8);
        half8f b0 = wp[0];
        half8f b1 = wp[64];
        half8f b2 = wp[128];
        half8f b3 = wp[192];
        float4f acc = {0.f, 0.f, 0.f, 0.f};
        acc = __builtin_amdgcn_mfma_f32_16x16x32_f16(a0, b0, acc, 0, 0, 0);
        acc = __builtin_amdgcn_mfma_f32_16x16x32_f16(a1, b1, acc, 0, 0, 0);
        acc = __builtin_amdgcn_mfma_f32_16x16x32_f16(a2, b2, acc, 0, 0, 0);
        acc = __builtin_amdgcn_mfma_f32_16x16x32_f16(a3, b3, acc, 0, 0, 0);
        float bi = bias[nt * 16 + l15];
#pragma unroll
        for (int r = 0; r < 4; ++r) {
            float v = acc[r] + bi;
            if (relu) v = fmaxf(v, 0.f);
            out[(size_t)(orow + r) * 64 + nt * 16 + l15] = f2h(v);
        }
    }
}

static __device__ __forceinline__ int lowerb(const int* a, int n, int key) {
    int lo = 0, hi = n;
    while (lo < hi) { int mid = (lo + hi) >> 1; if (a[mid] < key) lo = mid + 1; else hi = mid; }
    return lo;
}

// ---------- layer-3 collapse, stage 1: per-graph partial sums, 4 parts/graph
__global__ __launch_bounds__(256) void k_gsum(const unsigned short* __restrict__ h2,
        const int* __restrict__ rowptr, const int* __restrict__ col,
        const int* __restrict__ batch, float* __restrict__ S4) {
    __shared__ float red1[8][64];
    __shared__ float red2[8][64];
    const unsigned* Xu = (const unsigned*)h2;
    int g = blockIdx.x >> 2, part = blockIdx.x & 3;
    int t = threadIdx.x;
    int hw = t >> 5, c = t & 31;
    int ns = lowerb(batch, N_NODES, g);
    int ne = lowerb(batch, N_NODES, g + 1);
    int a0 = ns + (int)(((long long)(ne - ns) * part) >> 2);
    int a1 = ns + (int)(((long long)(ne - ns) * (part + 1)) >> 2);
    int es = rowptr[a0], ee = rowptr[a1];
    float alo = 0.f, ahi = 0.f;
    int nfull = (ee - es) >> 7;            // full 128-edge superblocks
    int e0 = es + hw * 16;
    for (int b = 0; b < nfull; ++b, e0 += 128) {
        unsigned v[16];
#pragma unroll
        for (int j = 0; j < 16; ++j)
            v[j] = Xu[(size_t)col[e0 + j] * 32 + c];
#pragma unroll
        for (int j = 0; j < 16; ++j) { alo += h_lo(v[j]); ahi += h_hi(v[j]); }
    }
    for (int e = es + nfull * 128 + hw; e < ee; e += 8) {
        unsigned v = Xu[(size_t)col[e] * 32 + c];
        alo += h_lo(v); ahi += h_hi(v);
    }
    float blo = 0.f, bhi = 0.f;
    for (int i = a0 + hw; i < a1; i += 8) {
        unsigned v = Xu[(size_t)i * 32 + c];
        blo += h_lo(v); bhi += h_hi(v);
    }
    red1[hw][2 * c] = alo; red1[hw][2 * c + 1] = ahi;
    red2[hw][2 * c] = blo; red2[hw][2 * c + 1] = bhi;
    __syncthreads();
    if (t < 64) {
        float v = 0.f;
#pragma unroll
        for (int s = 0; s < 8; ++s) v += red1[s][t];
        S4[(size_t)blockIdx.x * 128 + t] = v;
    } else if (t < 128) {
        float v = 0.f;
#pragma unroll
        for (int s = 0; s < 8; ++s) v += red2[s][t - 64];
        S4[(size_t)blockIdx.x * 128 + 64 + (t - 64)] = v;
    }
}

// ---------- layer-3 collapse, stage 2: pooled matmuls + head (all fp32)
__global__ __launch_bounds__(64) void k_head2(const float* __restrict__ S4,
        const int* __restrict__ batch,
        const float* __restrict__ wr3, const float* __restrict__ wo3,
        const float* __restrict__ b3,
        const float* __restrict__ wlin, const float* __restrict__ blin,
        float* __restrict__ out) {
    __shared__ float s1[64], s2[64], pl[64];
    int g = blockIdx.x, t = threadIdx.x;
    int ns = lowerb(batch, N_NODES, g);
    int ne = lowerb(batch, N_NODES, g + 1);
    float inv = 1.f / (float)((ne > ns) ? (ne - ns) : 1);
    const float* Sg = S4 + (size_t)g * 4 * 128;
    s1[t] = (Sg[t]       + Sg[128 + t]       + Sg[256 + t]       + Sg[384 + t]) * inv;
    s2[t] = (Sg[64 + t]  + Sg[192 + t]       + Sg[320 + t]       + Sg[448 + t]) * inv;
    __syncthreads();
    float acc = b3[t];
    for (int k = 0; k < 64; ++k)
        acc += s1[k] * wr3[t * 64 + k] + s2[k] * wo3[t * 64 + k];
    pl[t] = acc;
    __syncthreads();
    float myout = 0.f;
    for (int cls = 0; cls < NCLS; ++cls) {
        float vv = pl[t] * wlin[cls * 64 + t];
        for (int off = 32; off > 0; off >>= 1) vv += __shfl_xor(vv, off);
        if (t == cls) myout = vv + blin[cls];
    }
    if (t < NCLS) out[g * NCLS + t] = myout;
}

extern "C" void kernel_launch(void* const* d_in, const int* in_sizes, int n_in,
                              void* d_out, int out_size, void* d_ws, size_t ws_size,
                              hipStream_t stream) {
    const float* x     = (const float*)d_in[0];
    const int*   ei    = (const int*)d_in[1];
    const int*   batch = (const int*)d_in[2];
    const float* wr1 = (const float*)d_in[3];
    const float* b1  = (const float*)d_in[4];
    const float* wo1 = (const float*)d_in[5];
    const float* wr2 = (const float*)d_in[6];
    const float* b2  = (const float*)d_in[7];
    const float* wo2 = (const float*)d_in[8];
    const float* wr3 = (const float*)d_in[9];
    const float* b3  = (const float*)d_in[10];
    const float* wo3 = (const float*)d_in[11];
    const float* wlin = (const float*)d_in[12];
    const float* blin = (const float*)d_in[13];
    float* out = (float*)d_out;

    char* p = (char*)d_ws;
    auto alloc = [&](size_t bytes) { char* r = p; p += (bytes + 255) & ~(size_t)255; return r; };
    int*   rowptr  = (int*)alloc((N_NODES + 1) * sizeof(int));
    int*   hmat    = (int*)alloc((size_t)NTILE * CBPAD * sizeof(int));
    int*   obase   = (int*)alloc((size_t)NTILE * CBPAD * sizeof(int));
    int*   btot    = (int*)alloc(CBPAD * sizeof(int));
    int*   ebuf    = (int*)alloc((size_t)N_EDGES * sizeof(int));
    int*   col     = (int*)alloc((size_t)N_EDGES * sizeof(int));
    unsigned short* wf  = (unsigned short*)alloc(2 * 8192 * sizeof(unsigned short));
    unsigned short* xbf = (unsigned short*)alloc((size_t)N_NODES * 64 * 2);
    unsigned short* hA  = (unsigned short*)alloc((size_t)N_NODES * 64 * 2);
    unsigned short* hB  = (unsigned short*)alloc((size_t)N_NODES * 64 * 2);
    float* S4      = (float*)alloc((size_t)N_GRAPHS * 4 * 128 * sizeof(float));

    // CSR build (deterministic two-level counting sort) + prep, 4 launches
    k_histprep<<<NTILE + 5064, 256, 0, stream>>>(ei, x, wr1, wo1, wr2, wo2,
                                                 hmat, xbf, wf);
    k_scanT   <<<NCB,   256, 0, stream>>>(hmat, obase, btot);
    k_scatter2<<<NTILE, 256, 0, stream>>>(ei, obase, btot, ebuf);
    k_csr2    <<<NCB,   256, 0, stream>>>(ebuf, btot, rowptr, col);

    // layers 1+2: fused gather+linear (f16 packed accumulate + MFMA)
    k_gatherlin<<<N_NODES / 64, 256, 0, stream>>>(xbf, rowptr, col, wf,        b1, hA, 1);
    k_gatherlin<<<N_NODES / 64, 256, 0, stream>>>(hA,  rowptr, col, wf + 8192, b2, hB, 1);

    // layer 3 + pool collapsed
    k_gsum <<<N_GRAPHS * 4, 256, 0, stream>>>(hB, rowptr, col, batch, S4);
    k_head2<<<N_GRAPHS,     64,  0, stream>>>(S4, batch, wr3, wo3, b3, wlin, blin, out);
}

// Round 4
// 238.460 us; speedup vs baseline: 1.7342x; 1.0011x over previous
//
#include <hip/hip_runtime.h>

#define N_NODES  80000
#define N_EDGES  1280000
#define N_GRAPHS 512
#define DIM      64
#define NCLS     10

#define ETILE    2048
#define NTILE    625      // N_EDGES / ETILE exactly
#define NCB      625      // 128-node buckets; 80000/128 = 625 exactly
#define BSH      7        // log2(128)
#define HPAD     640

typedef _Float16 half8f __attribute__((ext_vector_type(8)));  // 8 f16 (4 VGPRs)
typedef float float4f __attribute__((ext_vector_type(4)));    // 4 fp32 acc

static __device__ __forceinline__ unsigned short f2h(float f) {
    _Float16 h = (_Float16)f;                 // v_cvt_f16_f32, RNE
    return __builtin_bit_cast(unsigned short, h);
}
static __device__ __forceinline__ float h_lo(unsigned v) {
    return (float)__builtin_bit_cast(_Float16, (unsigned short)(v & 0xFFFF));
}
static __device__ __forceinline__ float h_hi(unsigned v) {
    return (float)__builtin_bit_cast(_Float16, (unsigned short)(v >> 16));
}

// ---------- Pass A (merged): blocks [0,NTILE) per-tile histogram over
// 128-node buckets; blocks [NTILE, NTILE+5000) cast x->f16; rest pack W1/W2.
__global__ __launch_bounds__(256) void k_histprep(const int* __restrict__ ei,
        const float* __restrict__ x,
        const float* __restrict__ wr1, const float* __restrict__ wo1,
        const float* __restrict__ wr2, const float* __restrict__ wo2,
        int* __restrict__ hmat, unsigned short* __restrict__ xb,
        unsigned short* __restrict__ wf) {
    __shared__ int hist[NCB];
    int bid = blockIdx.x, t = threadIdx.x;
    if (bid < NTILE) {
        int tile = bid;
        for (int i = t; i < NCB; i += 256) hist[i] = 0;
        __syncthreads();
        int base = tile * ETILE;
        int end = base + ETILE;
        for (int i = base + t; i < end; i += 256)
            atomicAdd(&hist[ei[N_EDGES + i] >> BSH], 1);
        __syncthreads();
        for (int i = t; i < NCB; i += 256) hmat[tile * HPAD + i] = hist[i];
        return;
    }
    int pb = bid - NTILE;
    if (pb < 5000) {
        int i = pb * 256 + t;                   // N_NODES*16 float4s
        float4 v = ((const float4*)x)[i];
        ushort4 o;
        o.x = f2h(v.x); o.y = f2h(v.y); o.z = f2h(v.z); o.w = f2h(v.w);
        ((ushort4*)xb)[i] = o;
    } else {
        int idx = (pb - 5000) * 256 + t;        // < 2*8192
        int j = idx & 7, lane = (idx >> 3) & 63;
        int ks = (idx >> 9) & 3, nt = (idx >> 11) & 3, l = idx >> 13;
        int k = ks * 32 + ((lane >> 4) & 3) * 8 + j;
        int n = nt * 16 + (lane & 15);
        const float* wr = (l == 0) ? wr1 : wr2;
        const float* wo = (l == 0) ? wo1 : wo2;
        float val = (k < 64) ? wr[n * 64 + k] : wo[n * 64 + (k - 64)];
        wf[idx] = f2h(val);
    }
}

// ---------- Pass B1: per-bucket exclusive scan across 625 tiles (3 elems/thr)
__global__ __launch_bounds__(256) void k_scanT(const int* __restrict__ hmat,
        int* __restrict__ obase, int* __restrict__ btot) {
    __shared__ int sa[256], sb[256];
    int b = blockIdx.x, t = threadIdx.x;
    int j0 = 3 * t;
    int l0 = (j0     < NTILE) ? hmat[(j0    ) * HPAD + b] : 0;
    int l1 = (j0 + 1 < NTILE) ? hmat[(j0 + 1) * HPAD + b] : 0;
    int l2 = (j0 + 2 < NTILE) ? hmat[(j0 + 2) * HPAD + b] : 0;
    int s = l0 + l1 + l2;
    sa[t] = s; __syncthreads();
    int* sp = sa; int* dp = sb;
    for (int off = 1; off < 256; off <<= 1) {
        dp[t] = sp[t] + ((t >= off) ? sp[t - off] : 0);
        __syncthreads();
        int* tmp = sp; sp = dp; dp = tmp;
    }
    int ex = sp[t] - s;
    if (j0     < NTILE) obase[(j0    ) * HPAD + b] = ex;
    if (j0 + 1 < NTILE) obase[(j0 + 1) * HPAD + b] = ex + l0;
    if (j0 + 2 < NTILE) obase[(j0 + 2) * HPAD + b] = ex + l0 + l1;
    if (t == 255) btot[b] = sp[255];
}

// ---------- Pass B2: one-block scan of 625 bucket totals -> bucket bases
__global__ __launch_bounds__(256) void k_scanB(const int* __restrict__ btot,
        int* __restrict__ bucketbase, int* __restrict__ rowptr) {
    __shared__ int sa[256], sb[256];
    int t = threadIdx.x;
    int b0 = t * 5;
    int v0 = (b0     < NCB) ? btot[b0]     : 0;
    int v1 = (b0 + 1 < NCB) ? btot[b0 + 1] : 0;
    int v2 = (b0 + 2 < NCB) ? btot[b0 + 2] : 0;
    int v3 = (b0 + 3 < NCB) ? btot[b0 + 3] : 0;
    int v4 = (b0 + 4 < NCB) ? btot[b0 + 4] : 0;
    int s = v0 + v1 + v2 + v3 + v4;
    sa[t] = s; __syncthreads();
    int* sp = sa; int* dp = sb;
    for (int off = 1; off < 256; off <<= 1) {
        dp[t] = sp[t] + ((t >= off) ? sp[t - off] : 0);
        __syncthreads();
        int* tmp = sp; sp = dp; dp = tmp;
    }
    int ex = sp[t] - s;
    if (b0     < NCB) bucketbase[b0]     = ex;
    if (b0 + 1 < NCB) bucketbase[b0 + 1] = ex + v0;
    if (b0 + 2 < NCB) bucketbase[b0 + 2] = ex + v0 + v1;
    if (b0 + 3 < NCB) bucketbase[b0 + 3] = ex + v0 + v1 + v2;
    if (b0 + 4 < NCB) bucketbase[b0 + 4] = ex + v0 + v1 + v2 + v3;
    if (t == 0) { bucketbase[NCB] = N_EDGES; rowptr[N_NODES] = N_EDGES; }
}

// ---------- Pass C: scatter into bucket-sorted ebuf (deterministic runs)
__global__ __launch_bounds__(256) void k_scatter2(const int* __restrict__ ei,
        const int* __restrict__ obase, const int* __restrict__ bucketbase,
        int* __restrict__ ebuf) {
    __shared__ int cur[NCB];
    int tile = blockIdx.x, t = threadIdx.x;
    for (int i = t; i < NCB; i += 256)
        cur[i] = bucketbase[i] + obase[tile * HPAD + i];
    __syncthreads();
    int base = tile * ETILE;
    int end = base + ETILE;
    for (int i = base + t; i < end; i += 256) {
        int sv = ei[i], d = ei[N_EDGES + i];
        int p = atomicAdd(&cur[d >> BSH], 1);
        ebuf[p] = sv | ((d & 127) << 17);   // src:17 bits, local dst:7 bits
    }
}

// ---------- Pass D: per-bucket node-level CSR (128-node buckets), all in LDS
__global__ __launch_bounds__(256) void k_csr2(const int* __restrict__ ebuf,
        const int* __restrict__ bucketbase, int* __restrict__ rowptr,
        int* __restrict__ col) {
    __shared__ int cnt[128], cur[128];
    __shared__ int sa[128], sb[128];
    int b = blockIdx.x, t = threadIdx.x;
    int s = bucketbase[b], e = bucketbase[b + 1];
    if (t < 128) cnt[t] = 0;
    __syncthreads();
    for (int i = s + t; i < e; i += 256) atomicAdd(&cnt[ebuf[i] >> 17], 1);
    __syncthreads();
    if (t < 128) sa[t] = cnt[t];
    __syncthreads();
    int* sp = sa; int* dp = sb;
    for (int off = 1; off < 128; off <<= 1) {
        if (t < 128) dp[t] = sp[t] + ((t >= off) ? sp[t - off] : 0);
        __syncthreads();
        int* tmp = sp; sp = dp; dp = tmp;
    }
    if (t < 128) {
        int rowbase = s + sp[t] - cnt[t];
        cur[t] = rowbase;
        rowptr[b * 128 + t] = rowbase;      // 625*128 == 80000 exactly
    }
    __syncthreads();
    for (int i = s + t; i < e; i += 256) {
        int pk = ebuf[i];
        int p = atomicAdd(&cur[pk >> 17], 1);
        col[p] = pk & 0x1FFFF;
    }
}

// ---------- fused gather + MFMA linear: block = 64 nodes, wave = 16 nodes.
__global__ __launch_bounds__(256) void k_gatherlin(
        const unsigned short* __restrict__ Xin,
        const int* __restrict__ rowptr, const int* __restrict__ col,
        const unsigned short* __restrict__ wf, const float* __restrict__ bias,
        unsigned short* __restrict__ out, int relu) {
    __shared__ uint4 sAgg[64][9];
    const half8f* Xq = (const half8f*)Xin;
    int t = threadIdx.x, w = t >> 6, lane = t & 63;
    int e = lane >> 3, c = lane & 7;
    int nb = blockIdx.x * 64 + w * 16;          // first node of this wave
    int rp = (lane <= 16) ? rowptr[nb + lane] : 0;
    for (int n = 0; n < 16; ++n) {
        int start = __shfl(rp, n), end = __shfl(rp, n + 1);
        half8f acc = {};
        int base = start;
        for (; base + 16 <= end; base += 16) {   // 2 16B loads in flight
            int i0 = col[base + e];
            int i1 = col[base + 8 + e];
            half8f v0 = Xq[(size_t)i0 * 8 + c];
            half8f v1 = Xq[(size_t)i1 * 8 + c];
            acc = acc + v0;
            acc = acc + v1;
        }
        for (; base + 8 <= end; base += 8) {
            int i0 = col[base + e];
            acc = acc + Xq[(size_t)i0 * 8 + c];
        }
        int r = end - base;
        if (e < r) {
            int i0 = col[base + e];
            acc = acc + Xq[(size_t)i0 * 8 + c];
        }
#pragma unroll
        for (int off = 8; off < 64; off <<= 1) {
            uint4 au = __builtin_bit_cast(uint4, acc);
            uint4 bu;
            bu.x = __shfl_xor(au.x, off); bu.y = __shfl_xor(au.y, off);
            bu.z = __shfl_xor(au.z, off); bu.w = __shfl_xor(au.w, off);
            acc = acc + __builtin_bit_cast(half8f, bu);
        }
        if (e == 0) sAgg[w * 16 + n][c] = __builtin_bit_cast(uint4, acc);
    }
    // phase 2: out = act([agg|x] @ W + b)  (wave-private rows; lgkmcnt only)
    int quad = lane >> 4, l15 = lane & 15;
    int m = nb + l15;
    half8f a0 = *(const half8f*)&sAgg[w * 16 + l15][quad];
    half8f a1 = *(const half8f*)&sAgg[w * 16 + l15][4 + quad];
    const half8f* xr = (const half8f*)(Xin + (size_t)m * 64);
    half8f a2 = xr[quad];
    half8f a3 = xr[4 + quad];
    int orow = nb + quad * 4;
#pragma unroll
    for (int nt = 0; nt < 4; ++nt) {
        const half8f* wp = (const half8f*)(wf + ((size_t)(nt * 4) * 64 + lane) * 8);
        half8f b0 = wp[0];
        half8f b1 = wp[64];
        half8f b2 = wp[128];
        half8f b3 = wp[192];
        float4f acc = {0.f, 0.f, 0.f, 0.f};
        acc = __builtin_amdgcn_mfma_f32_16x16x32_f16(a0, b0, acc, 0, 0, 0);
        acc = __builtin_amdgcn_mfma_f32_16x16x32_f16(a1, b1, acc, 0, 0, 0);
        acc = __builtin_amdgcn_mfma_f32_16x16x32_f16(a2, b2, acc, 0, 0, 0);
        acc = __builtin_amdgcn_mfma_f32_16x16x32_f16(a3, b3, acc, 0, 0, 0);
        float bi = bias[nt * 16 + l15];
#pragma unroll
        for (int r = 0; r < 4; ++r) {
            float v = acc[r] + bi;
            if (relu) v = fmaxf(v, 0.f);
            out[(size_t)(orow + r) * 64 + nt * 16 + l15] = f2h(v);
        }
    }
}

static __device__ __forceinline__ int lowerb(const int* a, int n, int key) {
    int lo = 0, hi = n;
    while (lo < hi) { int mid = (lo + hi) >> 1; if (a[mid] < key) lo = mid + 1; else hi = mid; }
    return lo;
}

// ---------- layer-3 collapse, stage 1: per-graph partial sums, 4 parts/graph
// Rebuilt with the proven gather pattern: lane = (edge slot e of 8, 16B chunk
// c of 8); 8 lanes cover a 128B row; 2 loads in flight; f32 accumulate.
__global__ __launch_bounds__(256) void k_gsum(const unsigned short* __restrict__ h2,
        const int* __restrict__ rowptr, const int* __restrict__ col,
        const int* __restrict__ batch, float* __restrict__ S4) {
    __shared__ float red1[4][64];
    __shared__ float red2[4][64];
    const uint4* Xq = (const uint4*)h2;
    int g = blockIdx.x >> 2, part = blockIdx.x & 3;
    int t = threadIdx.x, w = t >> 6, lane = t & 63;
    int e = lane >> 3, c = lane & 7;
    int ns = lowerb(batch, N_NODES, g);
    int ne = lowerb(batch, N_NODES, g + 1);
    int a0 = ns + (int)(((long long)(ne - ns) * part) >> 2);
    int a1 = ns + (int)(((long long)(ne - ns) * (part + 1)) >> 2);
    int es = rowptr[a0], ee = rowptr[a1];
    float acc[8] = {0.f, 0.f, 0.f, 0.f, 0.f, 0.f, 0.f, 0.f};
    int idx = es + w * 8 + e;
    for (; idx + 32 < ee; idx += 64) {           // 2 uint4 loads in flight
        int i0 = col[idx];
        int i1 = col[idx + 32];
        uint4 v0 = Xq[(size_t)i0 * 8 + c];
        uint4 v1 = Xq[(size_t)i1 * 8 + c];
        acc[0] += h_lo(v0.x) + h_lo(v1.x); acc[1] += h_hi(v0.x) + h_hi(v1.x);
        acc[2] += h_lo(v0.y) + h_lo(v1.y); acc[3] += h_hi(v0.y) + h_hi(v1.y);
        acc[4] += h_lo(v0.z) + h_lo(v1.z); acc[5] += h_hi(v0.z) + h_hi(v1.z);
        acc[6] += h_lo(v0.w) + h_lo(v1.w); acc[7] += h_hi(v0.w) + h_hi(v1.w);
    }
    if (idx < ee) {
        int i0 = col[idx];
        uint4 v0 = Xq[(size_t)i0 * 8 + c];
        acc[0] += h_lo(v0.x); acc[1] += h_hi(v0.x);
        acc[2] += h_lo(v0.y); acc[3] += h_hi(v0.y);
        acc[4] += h_lo(v0.z); acc[5] += h_hi(v0.z);
        acc[6] += h_lo(v0.w); acc[7] += h_hi(v0.w);
    }
    float acc2[8] = {0.f, 0.f, 0.f, 0.f, 0.f, 0.f, 0.f, 0.f};
    for (int i = a0 + w * 8 + e; i < a1; i += 32) {
        uint4 v = Xq[(size_t)i * 8 + c];
        acc2[0] += h_lo(v.x); acc2[1] += h_hi(v.x);
        acc2[2] += h_lo(v.y); acc2[3] += h_hi(v.y);
        acc2[4] += h_lo(v.z); acc2[5] += h_hi(v.z);
        acc2[6] += h_lo(v.w); acc2[7] += h_hi(v.w);
    }
#pragma unroll
    for (int off = 8; off < 64; off <<= 1) {
#pragma unroll
        for (int j = 0; j < 8; ++j) {
            acc[j]  += __shfl_xor(acc[j],  off);
            acc2[j] += __shfl_xor(acc2[j], off);
        }
    }
    if (e == 0) {
#pragma unroll
        for (int j = 0; j < 8; ++j) {
            red1[w][c * 8 + j] = acc[j];
            red2[w][c * 8 + j] = acc2[j];
        }
    }
    __syncthreads();
    if (t < 64) {
        S4[(size_t)blockIdx.x * 128 + t] =
            red1[0][t] + red1[1][t] + red1[2][t] + red1[3][t];
    } else if (t < 128) {
        int d = t - 64;
        S4[(size_t)blockIdx.x * 128 + 64 + d] =
            red2[0][d] + red2[1][d] + red2[2][d] + red2[3][d];
    }
}

// ---------- layer-3 collapse, stage 2: pooled matmuls + head (all fp32)
__global__ __launch_bounds__(64) void k_head2(const float* __restrict__ S4,
        const int* __restrict__ batch,
        const float* __restrict__ wr3, const float* __restrict__ wo3,
        const float* __restrict__ b3,
        const float* __restrict__ wlin, const float* __restrict__ blin,
        float* __restrict__ out) {
    __shared__ float s1[64], s2[64], pl[64];
    int g = blockIdx.x, t = threadIdx.x;
    int ns = lowerb(batch, N_NODES, g);
    int ne = lowerb(batch, N_NODES, g + 1);
    float inv = 1.f / (float)((ne > ns) ? (ne - ns) : 1);
    const float* Sg = S4 + (size_t)g * 4 * 128;
    s1[t] = (Sg[t]       + Sg[128 + t]       + Sg[256 + t]       + Sg[384 + t]) * inv;
    s2[t] = (Sg[64 + t]  + Sg[192 + t]       + Sg[320 + t]       + Sg[448 + t]) * inv;
    __syncthreads();
    float acc = b3[t];
    for (int k = 0; k < 64; ++k)
        acc += s1[k] * wr3[t * 64 + k] + s2[k] * wo3[t * 64 + k];
    pl[t] = acc;
    __syncthreads();
    float myout = 0.f;
    for (int cls = 0; cls < NCLS; ++cls) {
        float vv = pl[t] * wlin[cls * 64 + t];
        for (int off = 32; off > 0; off >>= 1) vv += __shfl_xor(vv, off);
        if (t == cls) myout = vv + blin[cls];
    }
    if (t < NCLS) out[g * NCLS + t] = myout;
}

extern "C" void kernel_launch(void* const* d_in, const int* in_sizes, int n_in,
                              void* d_out, int out_size, void* d_ws, size_t ws_size,
                              hipStream_t stream) {
    const float* x     = (const float*)d_in[0];
    const int*   ei    = (const int*)d_in[1];
    const int*   batch = (const int*)d_in[2];
    const float* wr1 = (const float*)d_in[3];
    const float* b1  = (const float*)d_in[4];
    const float* wo1 = (const float*)d_in[5];
    const float* wr2 = (const float*)d_in[6];
    const float* b2  = (const float*)d_in[7];
    const float* wo2 = (const float*)d_in[8];
    const float* wr3 = (const float*)d_in[9];
    const float* b3  = (const float*)d_in[10];
    const float* wo3 = (const float*)d_in[11];
    const float* wlin = (const float*)d_in[12];
    const float* blin = (const float*)d_in[13];
    float* out = (float*)d_out;

    char* p = (char*)d_ws;
    auto alloc = [&](size_t bytes) { char* r = p; p += (bytes + 255) & ~(size_t)255; return r; };
    int*   rowptr  = (int*)alloc((N_NODES + 1) * sizeof(int));
    int*   hmat    = (int*)alloc((size_t)NTILE * HPAD * sizeof(int));
    int*   obase   = (int*)alloc((size_t)NTILE * HPAD * sizeof(int));
    int*   btot    = (int*)alloc(HPAD * sizeof(int));
    int*   bucketbase = (int*)alloc((NCB + 1) * sizeof(int));
    int*   ebuf    = (int*)alloc((size_t)N_EDGES * sizeof(int));
    int*   col     = (int*)alloc((size_t)N_EDGES * sizeof(int));
    unsigned short* wf  = (unsigned short*)alloc(2 * 8192 * sizeof(unsigned short));
    unsigned short* xbf = (unsigned short*)alloc((size_t)N_NODES * 64 * 2);
    unsigned short* hA  = (unsigned short*)alloc((size_t)N_NODES * 64 * 2);
    unsigned short* hB  = (unsigned short*)alloc((size_t)N_NODES * 64 * 2);
    float* S4      = (float*)alloc((size_t)N_GRAPHS * 4 * 128 * sizeof(float));

    // CSR build (deterministic two-level counting sort) + prep
    k_histprep<<<NTILE + 5064, 256, 0, stream>>>(ei, x, wr1, wo1, wr2, wo2,
                                                 hmat, xbf, wf);
    k_scanT   <<<NCB,   256, 0, stream>>>(hmat, obase, btot);
    k_scanB   <<<1,     256, 0, stream>>>(btot, bucketbase, rowptr);
    k_scatter2<<<NTILE, 256, 0, stream>>>(ei, obase, bucketbase, ebuf);
    k_csr2    <<<NCB,   256, 0, stream>>>(ebuf, bucketbase, rowptr, col);

    // layers 1+2: fused gather+linear (f16 packed accumulate + MFMA)
    k_gatherlin<<<N_NODES / 64, 256, 0, stream>>>(xbf, rowptr, col, wf,        b1, hA, 1);
    k_gatherlin<<<N_NODES / 64, 256, 0, stream>>>(hA,  rowptr, col, wf + 8192, b2, hB, 1);

    // layer 3 + pool collapsed
    k_gsum <<<N_GRAPHS * 4, 256, 0, stream>>>(hB, rowptr, col, batch, S4);
    k_head2<<<N_GRAPHS,     64,  0, stream>>>(S4, batch, wr3, wo3, b3, wlin, blin, out);
}